// Round 10
// baseline (568.316 us; speedup 1.0000x reference)
//
#include <hip/hip_runtime.h>

#define BATCH 8
#define CH    64
#define HH    112
#define WW    112
#define HW    (HH * WW)          // 12544
#define NP    (BATCH * HW)       // 100352 pixels
#define TAPS  25
#define MIDC  256
#define PIX   64                 // pixels per block (= 1 wave-width group)
#define CPW   16                 // channels per wave (4 waves * 16 = 64)
#define NBLK  (NP / PIX)         // 1568 blocks
#define NXCD  8
#define CPX   (NBLK / NXCD)      // 196 blocks per XCD == blocks per image
#define WPAD  28                 // padded o-stride (112 B, 16B-aligned rows)
#define WSLAB (CH * WPAD)        // 1792 floats per tap slab (7168 B)

// ---------------------------------------------------------------------------
// Kernel A: fold conv2 (1x1, 256->25) into conv1 weights.
// Layout: weff[tap][c][28] padded in global -> every per-(tap,c) weight run
// is 16B-aligned for float4 vector loads with immediate offsets.
//   weff[((tap*CH)+c)*28 + o] = sum_mid w2[o][mid] * w1[mid][c][tap]
// ---------------------------------------------------------------------------
#define WEFF_N   (CH * TAPS * TAPS)   // 40000 logical outputs
#define WEFF_TOT (WEFF_N + TAPS)      // + beff
#define WEFF_PAD (TAPS * WSLAB)       // 44800 padded floats
__global__ __launch_bounds__(256) void weff_kernel(
    const float* __restrict__ w1, const float* __restrict__ b1,
    const float* __restrict__ w2, const float* __restrict__ b2,
    float* __restrict__ weff, float* __restrict__ beff) {
  __shared__ float part[3][64];              // chunks 1..3 park partials
  const int lane  = threadIdx.x & 63;
  const int chunk = threadIdx.x >> 6;        // mid in [chunk*64, chunk*64+64)
  const int id    = blockIdx.x * 64 + lane;

  float acc = 0.f;
  if (id < WEFF_N) {
    const int tap = id % TAPS;
    const int t2  = id / TAPS;
    const int o   = t2 % TAPS;
    const int c   = t2 / TAPS;
    const float* w2o = w2 + o * MIDC + chunk * 64;
    const float* w1p = w1 + ((size_t)(chunk * 64) * CH + c) * TAPS + tap;
    float a0 = 0.f, a1 = 0.f;
    #pragma unroll 8
    for (int m = 0; m < 64; m += 2) {
      a0 = fmaf(w1p[(size_t)m       * CH * TAPS], w2o[m],     a0);
      a1 = fmaf(w1p[(size_t)(m + 1) * CH * TAPS], w2o[m + 1], a1);
    }
    acc = a0 + a1;
  } else if (id < WEFF_TOT) {
    const int o = id - WEFF_N;
    const float* w2o = w2 + o * MIDC + chunk * 64;
    const float* b1p = b1 + chunk * 64;
    #pragma unroll 8
    for (int m = 0; m < 64; ++m) acc = fmaf(w2o[m], b1p[m], acc);
  }

  if (chunk) part[chunk - 1][lane] = acc;
  __syncthreads();
  if (chunk == 0 && id < WEFF_TOT) {
    float r = acc + part[0][lane] + part[1][lane] + part[2][lane];
    if (id < WEFF_N) {
      const int tap = id % TAPS;
      const int t2  = id / TAPS;
      const int o   = t2 % TAPS;
      const int c   = t2 / TAPS;
      weff[((size_t)tap * CH + c) * WPAD + o] = r;     // padded [tap][c][28]
    } else {
      beff[id - WEFF_N] = r + b2[id - WEFF_N];
    }
  }
}

// ---------------------------------------------------------------------------
// Kernel B. R10: EXACT R6 structure; ONLY the weight load path changed.
// R6 consumed weights via s_load (SMEM is out-of-order -> lgkmcnt(0) drains
// every few FMAs; SGPRs can't hold a tap's 400 floats -> ~400 drains/thread
// = the pinned 55% VALUBusy). R10 forces the VECTOR path with an opaque-zero
// VGPR offset (compiler can't prove uniformity -> global_load_dwordx4).
// Uniform address across lanes = one cacheline broadcast per instruction;
// vmcnt-counted loads pipeline under the FMA stream with NO drains and NO
// extra live state (no LDS staging, no cross-barrier prefetch regs — the
// R7/R8/R9 spill killers are absent).
// ---------------------------------------------------------------------------
__global__ __launch_bounds__(256, 6) void picanet_main(
    const float* __restrict__ x, const float* __restrict__ weff,
    const float* __restrict__ beff, float* __restrict__ out) {
  __shared__ float red[2 * PIX * TAPS];       // 12.8 KB

  const int lane = threadIdx.x & 63;
  const int wave = threadIdx.x >> 6;
  const int c0 = __builtin_amdgcn_readfirstlane(wave * CPW);

  // Opaque zero in a VGPR: defeats uniform-address scalarization so weight
  // loads stay on the vector (vmcnt, pipelinable) path.
  int voff = 0;
  asm volatile("" : "+v"(voff));

  // XCD-aware bijective remap: image b pinned to XCD b (3.2 MB < 4 MB L2).
  const int lb = (blockIdx.x & (NXCD - 1)) * CPX + (blockIdx.x >> 3);
  const int p  = lb * PIX + lane;             // NP % 64 == 0, no tail
  const int b  = p / HW;
  const int hw = p % HW;
  const int h  = hw / WW;
  const int w  = hw % WW;

  const float* xb = x + (size_t)b * CH * HW + (size_t)c0 * HW;

  // ---- Phase 1: partial logits over this wave's 16 channels ----
  float s[TAPS];
  #pragma unroll
  for (int o = 0; o < TAPS; ++o) s[o] = 0.f;

  #pragma unroll 1
  for (int tap = 0; tap < TAPS; ++tap) {
    int i = tap / 5, j = tap % 5;
    int yy = h + 2 * i - 4;
    int xx = w + 2 * j - 4;
    if (yy >= 0 && yy < HH && xx >= 0 && xx < WW) {
      const float* xp = xb + yy * WW + xx;
      const float* wt = weff + (size_t)tap * WSLAB + (size_t)c0 * WPAD + voff;
      float xv[CPW];
      #pragma unroll
      for (int c = 0; c < CPW; ++c) xv[c] = xp[(size_t)c * HW];
      #pragma unroll
      for (int c = 0; c < CPW; ++c) {
        const float* wp = wt + c * WPAD;      // 16B-aligned, imm offsets
        float4 w0 = *(const float4*)(wp);
        float4 w1 = *(const float4*)(wp + 4);
        float4 w2 = *(const float4*)(wp + 8);
        float4 w3 = *(const float4*)(wp + 12);
        float4 w4 = *(const float4*)(wp + 16);
        float4 w5 = *(const float4*)(wp + 20);
        float  wl = wp[24];
        float xc = xv[c];
        s[0]  = fmaf(xc, w0.x, s[0]);
        s[1]  = fmaf(xc, w0.y, s[1]);
        s[2]  = fmaf(xc, w0.z, s[2]);
        s[3]  = fmaf(xc, w0.w, s[3]);
        s[4]  = fmaf(xc, w1.x, s[4]);
        s[5]  = fmaf(xc, w1.y, s[5]);
        s[6]  = fmaf(xc, w1.z, s[6]);
        s[7]  = fmaf(xc, w1.w, s[7]);
        s[8]  = fmaf(xc, w2.x, s[8]);
        s[9]  = fmaf(xc, w2.y, s[9]);
        s[10] = fmaf(xc, w2.z, s[10]);
        s[11] = fmaf(xc, w2.w, s[11]);
        s[12] = fmaf(xc, w3.x, s[12]);
        s[13] = fmaf(xc, w3.y, s[13]);
        s[14] = fmaf(xc, w3.z, s[14]);
        s[15] = fmaf(xc, w3.w, s[15]);
        s[16] = fmaf(xc, w4.x, s[16]);
        s[17] = fmaf(xc, w4.y, s[17]);
        s[18] = fmaf(xc, w4.z, s[18]);
        s[19] = fmaf(xc, w4.w, s[19]);
        s[20] = fmaf(xc, w5.x, s[20]);
        s[21] = fmaf(xc, w5.y, s[21]);
        s[22] = fmaf(xc, w5.z, s[22]);
        s[23] = fmaf(xc, w5.w, s[23]);
        s[24] = fmaf(xc, wl,   s[24]);
      }
    }
  }

  // ---- Tree reduce across waves (12.8 KB) ----
  if (wave >= 2) {
    float* dst = red + (wave - 2) * (PIX * TAPS);
    #pragma unroll
    for (int o = 0; o < TAPS; ++o) dst[lane * TAPS + o] = s[o];
  }
  __syncthreads();
  if (wave < 2) {
    const float* srcp = red + wave * (PIX * TAPS);
    #pragma unroll
    for (int o = 0; o < TAPS; ++o) s[o] += srcp[lane * TAPS + o];
  }
  if (wave == 1) {
    float* dst = red + (PIX * TAPS);
    #pragma unroll
    for (int o = 0; o < TAPS; ++o) dst[lane * TAPS + o] = s[o];
  }
  __syncthreads();

  // ---- Softmax: full 64-lane wave 0, one pixel per lane ----
  if (wave == 0) {
    const float* srcp = red + (PIX * TAPS);
    float t[TAPS];
    #pragma unroll
    for (int o = 0; o < TAPS; ++o)
      t[o] = s[o] + srcp[lane * TAPS + o] + beff[o];
    float m = t[0];
    #pragma unroll
    for (int o = 1; o < TAPS; ++o) m = fmaxf(m, t[o]);
    float sum = 0.f;
    #pragma unroll
    for (int o = 0; o < TAPS; ++o) { t[o] = __expf(t[o] - m); sum += t[o]; }
    float inv = 1.f / sum;
    #pragma unroll
    for (int o = 0; o < TAPS; ++o) red[lane * TAPS + o] = t[o] * inv;
  }
  __syncthreads();

  // ---- Phase 2: out[b,c,h,w] = sum_tap sfin[tap] * x[b,c,tap(h,w)] ----
  float acc[CPW];
  #pragma unroll
  for (int c = 0; c < CPW; ++c) acc[c] = 0.f;

  #pragma unroll 1
  for (int tap = 0; tap < TAPS; ++tap) {
    int i = tap / 5, j = tap % 5;
    int yy = h + 2 * i - 4;
    int xx = w + 2 * j - 4;
    float sv = red[lane * TAPS + tap];
    if (yy >= 0 && yy < HH && xx >= 0 && xx < WW) {
      const float* xp = xb + yy * WW + xx;
      #pragma unroll
      for (int c = 0; c < CPW; ++c)
        acc[c] = fmaf(sv, xp[(size_t)c * HW], acc[c]);
    }
  }

  float* ob = out + (size_t)b * CH * HW + (size_t)c0 * HW + hw;
  #pragma unroll
  for (int c = 0; c < CPW; ++c) ob[c * HW] = acc[c];
}

extern "C" void kernel_launch(void* const* d_in, const int* in_sizes, int n_in,
                              void* d_out, int out_size, void* d_ws, size_t ws_size,
                              hipStream_t stream) {
  const float* x  = (const float*)d_in[0];
  const float* w1 = (const float*)d_in[1];
  const float* b1 = (const float*)d_in[2];
  const float* w2 = (const float*)d_in[3];
  const float* b2 = (const float*)d_in[4];
  float* out  = (float*)d_out;
  float* weff = (float*)d_ws;                       // 44800 padded floats
  float* beff = weff + WEFF_PAD;                    // 25 floats

  weff_kernel<<<(WEFF_TOT + 63) / 64, 256, 0, stream>>>(
      w1, b1, w2, b2, weff, beff);
  picanet_main<<<NBLK, 256, 0, stream>>>(x, weff, beff, out);
}

// Round 11
// 248.673 us; speedup vs baseline: 2.2854x; 2.2854x over previous
//
#include <hip/hip_runtime.h>

#define BATCH 8
#define CH    64
#define HH    112
#define WW    112
#define HW    (HH * WW)          // 12544
#define NP    (BATCH * HW)       // 100352 pixels
#define TAPS  25
#define MIDC  256
#define PIX   64                 // pixels per block (= 1 wave-width group)
#define CPW   16                 // channels per wave (4 waves * 16 = 64)
#define NBLK  (NP / PIX)         // 1568 blocks
#define NXCD  8
#define CPX   (NBLK / NXCD)      // 196 blocks per XCD == blocks per image
#define WPAD  28                 // padded o-stride (112 B, 16B-aligned rows)
#define WSLAB (CH * WPAD)        // 1792 floats per tap slab (7168 B)

// ---------------------------------------------------------------------------
// Kernel A: fold conv2 (1x1, 256->25) into conv1 weights.
// Padded layout weff[tap][c][28]: per-tap slab = 448 float4s, staging in the
// main kernel is a pure linear float4 copy; LDS rows 16B-aligned.
//   weff[((tap*CH)+c)*28 + o] = sum_mid w2[o][mid] * w1[mid][c][tap]
// ---------------------------------------------------------------------------
#define WEFF_N   (CH * TAPS * TAPS)   // 40000 logical outputs
#define WEFF_TOT (WEFF_N + TAPS)      // + beff
#define WEFF_PAD (TAPS * WSLAB)       // 44800 padded floats
__global__ __launch_bounds__(256) void weff_kernel(
    const float* __restrict__ w1, const float* __restrict__ b1,
    const float* __restrict__ w2, const float* __restrict__ b2,
    float* __restrict__ weff, float* __restrict__ beff) {
  __shared__ float part[3][64];              // chunks 1..3 park partials
  const int lane  = threadIdx.x & 63;
  const int chunk = threadIdx.x >> 6;        // mid in [chunk*64, chunk*64+64)
  const int id    = blockIdx.x * 64 + lane;

  float acc = 0.f;
  if (id < WEFF_N) {
    const int tap = id % TAPS;
    const int t2  = id / TAPS;
    const int o   = t2 % TAPS;
    const int c   = t2 / TAPS;
    const float* w2o = w2 + o * MIDC + chunk * 64;
    const float* w1p = w1 + ((size_t)(chunk * 64) * CH + c) * TAPS + tap;
    float a0 = 0.f, a1 = 0.f;
    #pragma unroll 8
    for (int m = 0; m < 64; m += 2) {
      a0 = fmaf(w1p[(size_t)m       * CH * TAPS], w2o[m],     a0);
      a1 = fmaf(w1p[(size_t)(m + 1) * CH * TAPS], w2o[m + 1], a1);
    }
    acc = a0 + a1;
  } else if (id < WEFF_TOT) {
    const int o = id - WEFF_N;
    const float* w2o = w2 + o * MIDC + chunk * 64;
    const float* b1p = b1 + chunk * 64;
    #pragma unroll 8
    for (int m = 0; m < 64; ++m) acc = fmaf(w2o[m], b1p[m], acc);
  }

  if (chunk) part[chunk - 1][lane] = acc;
  __syncthreads();
  if (chunk == 0 && id < WEFF_TOT) {
    float r = acc + part[0][lane] + part[1][lane] + part[2][lane];
    if (id < WEFF_N) {
      const int tap = id % TAPS;
      const int t2  = id / TAPS;
      const int o   = t2 % TAPS;
      const int c   = t2 / TAPS;
      weff[((size_t)tap * CH + c) * WPAD + o] = r;     // padded [tap][c][28]
    } else {
      beff[id - WEFF_N] = r + b2[id - WEFF_N];
    }
  }
}

// ---------------------------------------------------------------------------
// Kernel B. R11: R6 structure; weights LDS-staged per tap (spill-free).
// WHY: R6's phase 1 is barrier-free, so 6 free-running waves/SIMD should
// hide per-wave latency; VALUBusy pinned at 55% => a SHARED resource
// saturates. s_loads fetch weights PER-WAVE (no lane amortization): ~1 MB
// scalar traffic/CU/round through a thrashed 16KB K$ and a shallow SQC miss
// queue. Fix: stage each tap's 7KB slab in LDS once per BLOCK (x4 amortize)
// and consume via wave-uniform broadcast ds_read_b128 (in-order lgkm).
// Spill-free: staging regs are transient (load -> ds_write immediately);
// nothing lives across a barrier. R8's pw[7] / R9's nv0-nv1 mistakes absent.
// x-path / reduce / softmax / phase 2: verbatim R6.
// ---------------------------------------------------------------------------
__global__ __launch_bounds__(256, 6) void picanet_main(
    const float* __restrict__ x, const float* __restrict__ weff,
    const float* __restrict__ beff, float* __restrict__ out) {
  __shared__ float wlds[WSLAB];               //  7.0 KB weight slab (one tap)
  __shared__ float red[2 * PIX * TAPS];       // 12.8 KB  (total 19.97 KB)

  const int tid  = threadIdx.x;
  const int lane = tid & 63;
  const int wave = tid >> 6;
  const int c0 = __builtin_amdgcn_readfirstlane(wave * CPW);

  // XCD-aware bijective remap: image b pinned to XCD b (3.2 MB < 4 MB L2).
  const int lb = (blockIdx.x & (NXCD - 1)) * CPX + (blockIdx.x >> 3);
  const int p  = lb * PIX + lane;             // NP % 64 == 0, no tail
  const int b  = p / HW;
  const int hw = p % HW;
  const int h  = hw / WW;
  const int w  = hw % WW;

  const float* xb = x + (size_t)b * CH * HW + (size_t)c0 * HW;

  // ---- Phase 1: partial logits; per-tap weight slab staged in LDS ----
  float s[TAPS];
  #pragma unroll
  for (int o = 0; o < TAPS; ++o) s[o] = 0.f;

  #pragma unroll 1
  for (int tap = 0; tap < TAPS; ++tap) {
    __syncthreads();                          // prior tap's wlds reads done
    {
      // 448 float4s staged by 256 threads; transient regs, no cross-barrier
      // lifetime. Loads are L2-hits (weff is 179KB, hot in every XCD L2).
      const float4* wg4 = (const float4*)(weff + (size_t)tap * WSLAB);
      float4* wl4 = (float4*)wlds;
      float4 t0 = wg4[tid];
      wl4[tid] = t0;
      if (tid < 192) {
        float4 t1 = wg4[256 + tid];
        wl4[256 + tid] = t1;
      }
    }
    __syncthreads();                          // slab visible to all waves

    int i = tap / 5, j = tap % 5;
    int yy = h + 2 * i - 4;
    int xx = w + 2 * j - 4;
    if (yy >= 0 && yy < HH && xx >= 0 && xx < WW) {
      const float* xp = xb + yy * WW + xx;
      float xv[CPW];
      #pragma unroll
      for (int c = 0; c < CPW; ++c) xv[c] = xp[(size_t)c * HW];
      #pragma unroll
      for (int c = 0; c < CPW; ++c) {
        // wave-uniform address -> broadcast ds_read_b128, in-order lgkm
        const float* wp = wlds + (c0 + c) * WPAD;
        #pragma unroll
        for (int o = 0; o < TAPS; ++o) s[o] = fmaf(xv[c], wp[o], s[o]);
      }
    }
  }
  __syncthreads();                            // last tap's wlds reads done

  // ---- Tree reduce across waves (12.8 KB) ----
  if (wave >= 2) {
    float* dst = red + (wave - 2) * (PIX * TAPS);
    #pragma unroll
    for (int o = 0; o < TAPS; ++o) dst[lane * TAPS + o] = s[o];
  }
  __syncthreads();
  if (wave < 2) {
    const float* srcp = red + wave * (PIX * TAPS);
    #pragma unroll
    for (int o = 0; o < TAPS; ++o) s[o] += srcp[lane * TAPS + o];
  }
  if (wave == 1) {
    float* dst = red + (PIX * TAPS);
    #pragma unroll
    for (int o = 0; o < TAPS; ++o) dst[lane * TAPS + o] = s[o];
  }
  __syncthreads();

  // ---- Softmax: full 64-lane wave 0, one pixel per lane ----
  if (wave == 0) {
    const float* srcp = red + (PIX * TAPS);
    float t[TAPS];
    #pragma unroll
    for (int o = 0; o < TAPS; ++o)
      t[o] = s[o] + srcp[lane * TAPS + o] + beff[o];
    float m = t[0];
    #pragma unroll
    for (int o = 1; o < TAPS; ++o) m = fmaxf(m, t[o]);
    float sum = 0.f;
    #pragma unroll
    for (int o = 0; o < TAPS; ++o) { t[o] = __expf(t[o] - m); sum += t[o]; }
    float inv = 1.f / sum;
    #pragma unroll
    for (int o = 0; o < TAPS; ++o) red[lane * TAPS + o] = t[o] * inv;
  }
  __syncthreads();

  // ---- Phase 2: out[b,c,h,w] = sum_tap sfin[tap] * x[b,c,tap(h,w)] ----
  float acc[CPW];
  #pragma unroll
  for (int c = 0; c < CPW; ++c) acc[c] = 0.f;

  #pragma unroll 1
  for (int tap = 0; tap < TAPS; ++tap) {
    int i = tap / 5, j = tap % 5;
    int yy = h + 2 * i - 4;
    int xx = w + 2 * j - 4;
    float sv = red[lane * TAPS + tap];
    if (yy >= 0 && yy < HH && xx >= 0 && xx < WW) {
      const float* xp = xb + yy * WW + xx;
      #pragma unroll
      for (int c = 0; c < CPW; ++c)
        acc[c] = fmaf(sv, xp[(size_t)c * HW], acc[c]);
    }
  }

  float* ob = out + (size_t)b * CH * HW + (size_t)c0 * HW + hw;
  #pragma unroll
  for (int c = 0; c < CPW; ++c) ob[c * HW] = acc[c];
}

extern "C" void kernel_launch(void* const* d_in, const int* in_sizes, int n_in,
                              void* d_out, int out_size, void* d_ws, size_t ws_size,
                              hipStream_t stream) {
  const float* x  = (const float*)d_in[0];
  const float* w1 = (const float*)d_in[1];
  const float* b1 = (const float*)d_in[2];
  const float* w2 = (const float*)d_in[3];
  const float* b2 = (const float*)d_in[4];
  float* out  = (float*)d_out;
  float* weff = (float*)d_ws;                       // 44800 padded floats
  float* beff = weff + WEFF_PAD;                    // 25 floats

  weff_kernel<<<(WEFF_TOT + 63) / 64, 256, 0, stream>>>(
      w1, b1, w2, b2, weff, beff);
  picanet_main<<<NBLK, 256, 0, stream>>>(x, weff, beff, out);
}